// Round 17
// baseline (125.193 us; speedup 1.0000x reference)
//
#include <hip/hip_runtime.h>

#define D 128
#define FILL_CHUNK 2048

typedef short bf16x8 __attribute__((ext_vector_type(8)));
typedef float f32x4 __attribute__((ext_vector_type(4)));

// ---------- bf16 helpers ----------
static __device__ __forceinline__ unsigned int f2bf(float f) {
  unsigned int u = __float_as_uint(f);
  return (u + 0x7FFFu + ((u >> 16) & 1u)) >> 16;   // RNE
}
static __device__ __forceinline__ unsigned int pack2bf(float lo, float hi) {
  return f2bf(lo) | (f2bf(hi) << 16);
}
static __device__ __forceinline__ float bf_lo(unsigned int v) {
  return __uint_as_float(v << 16);
}
static __device__ __forceinline__ float bf_hi(unsigned int v) {
  return __uint_as_float(v & 0xFFFF0000u);
}
// permuted deg index: partition (n&7) owns a contiguous NP8-counter region
static __device__ __forceinline__ int degIdx(int n, int NP8) {
  return (n & 7) * NP8 + (n >> 3);
}

// ---------------- prep: weights (blocks 0-2) + zero deg + pack edges (src<<16|dst) ----------------

__global__ __launch_bounds__(256) void k_prep(const float* __restrict__ W1,
                                              const float* __restrict__ Wg,
                                              const float* __restrict__ W2,
                                              unsigned short* __restrict__ WT,
                                              int* __restrict__ deg, int ZN,
                                              const int* __restrict__ ei, int E,
                                              unsigned int* __restrict__ pk) {
  const int t = threadIdx.x;
  if (blockIdx.x < 3) {
    const float* W = (blockIdx.x == 0) ? W1 : (blockIdx.x == 1) ? Wg : W2;
    unsigned short* T = WT + blockIdx.x * 16384;
    for (int idx = t; idx < 16384; idx += 256) {
      int k = idx >> 7, j = idx & 127;
      T[j * 128 + k] = (unsigned short)f2bf(W[idx]);
    }
    return;
  }
  const int nzb = (ZN + 255) >> 8;
  int b = blockIdx.x - 3;
  if (b < nzb) {
    int i = b * 256 + t;
    if (i < ZN) deg[i] = 0;
    return;
  }
  // pack 2048 edges/block: pk[e] = (src<<16)|dst, sentinel 0xFFFFFFFF past E
  b -= nzb;
  const int base = b * FILL_CHUNK;
#pragma unroll
  for (int i = 0; i < 2; ++i) {
    int e0 = base + (t + i * 256) * 4;
    uint4 o;
    if (e0 + 3 < E) {
      int4 s4 = *(const int4*)(ei + e0);
      int4 d4 = *(const int4*)(ei + E + e0);
      o.x = (((unsigned)s4.x) << 16) | (unsigned)d4.x;
      o.y = (((unsigned)s4.y) << 16) | (unsigned)d4.y;
      o.z = (((unsigned)s4.z) << 16) | (unsigned)d4.z;
      o.w = (((unsigned)s4.w) << 16) | (unsigned)d4.w;
    } else {
      unsigned tv[4];
#pragma unroll
      for (int j = 0; j < 4; ++j) {
        int e = e0 + j;
        tv[j] = (e < E) ? ((((unsigned)ei[e]) << 16) | (unsigned)ei[E + e]) : 0xFFFFFFFFu;
      }
      o = make_uint4(tv[0], tv[1], tv[2], tv[3]);
    }
    ((uint4*)pk)[(base >> 2) + t + i * 256] = o;
  }
}

// ---------------- fused degree + CSR fill from packed edges, XCD-affine partitions ----------------
// Partition p = blockIdx%8 handles dsts with (dst&7)==p. Bucket lines (csr16, node-major)
// AND deg counter lines (permuted layout) are both single-partition-owned -> single-XCD
// under the round-robin block->XCD heuristic (correctness mapping-independent).

__global__ __launch_bounds__(256) void k_fill(const unsigned int* __restrict__ pk,
                                              int* __restrict__ deg,
                                              unsigned short* __restrict__ csr16,
                                              int cap, int NP8) {
  const unsigned p = blockIdx.x & 7;
  const int i4base = (blockIdx.x >> 3) * (FILL_CHUNK / 4);
  const uint4* pk4 = (const uint4*)pk;
  const int t = threadIdx.x;
  const int pbase = (int)p * NP8;
#pragma unroll
  for (int i = 0; i < 2; ++i) {
    uint4 w = pk4[i4base + i * 256 + t];
    unsigned vv[4] = {w.x, w.y, w.z, w.w};
#pragma unroll
    for (int j = 0; j < 4; ++j) {
      unsigned v = vv[j];
      if (v != 0xFFFFFFFFu && (v & 7u) == p) {
        int d = (int)(v & 0xFFFFu);
        int s = (int)(v >> 16);
        int pos = atomicAdd(&deg[pbase + (d >> 3)], 1);
        if (pos < cap)
          csr16[(size_t)d * cap + pos] = (unsigned short)s;
      }
    }
  }
}

// ---------------- MFMA MLP: h2 = rsqrt(deg+1) * ((relu(x@W1+b1)) @ Wg), bf16 out ----------------

__global__ __launch_bounds__(256) void k_mlp(const float* __restrict__ x,
                                             const unsigned short* __restrict__ W1T,
                                             const float* __restrict__ b1,
                                             const unsigned short* __restrict__ WgT,
                                             const int* __restrict__ deg,
                                             unsigned short* __restrict__ h2, int N, int NP8) {
  __shared__ unsigned short xs[64][136];   // A tile (x, then h1)
  __shared__ unsigned short wB[128][136];  // B^T tile (W1T, then WgT)
  const int t = threadIdx.x;
  const int wave = t >> 6, lane = t & 63;
  const int rowBase = blockIdx.x * 64;
  const int ar = lane & 15, kg = lane >> 4;

#pragma unroll
  for (int i = 0; i < 8; ++i) {
    int idx = t + i * 256;
    int r = idx >> 5, c4 = (idx & 31) << 2;
    float4 v = make_float4(0.f, 0.f, 0.f, 0.f);
    int gr = rowBase + r;
    if (gr < N) v = *(const float4*)(x + (size_t)gr * D + c4);
    *(unsigned int*)&xs[r][c4]     = pack2bf(v.x, v.y);
    *(unsigned int*)&xs[r][c4 + 2] = pack2bf(v.z, v.w);
  }
#pragma unroll
  for (int i = 0; i < 8; ++i) {
    int idx = t + i * 256;
    int r = idx >> 4, c8 = (idx & 15) << 3;
    *(uint4*)&wB[r][c8] = *(const uint4*)(W1T + r * 128 + c8);
  }
  __syncthreads();

  float bias1[8];
#pragma unroll
  for (int cf = 0; cf < 8; ++cf) bias1[cf] = b1[cf * 16 + ar];
  float dnv[4];
#pragma unroll
  for (int reg = 0; reg < 4; ++reg) {
    int gr = rowBase + wave * 16 + 4 * kg + reg;
    dnv[reg] = (gr < N) ? rsqrtf((float)(deg[degIdx(gr, NP8)] + 1)) : 0.f;
  }

  f32x4 acc[8];
#pragma unroll
  for (int cf = 0; cf < 8; ++cf) acc[cf] = (f32x4){0.f, 0.f, 0.f, 0.f};
#pragma unroll
  for (int ks = 0; ks < 4; ++ks) {
    bf16x8 a = *(const bf16x8*)&xs[wave * 16 + ar][ks * 32 + kg * 8];
#pragma unroll
    for (int cf = 0; cf < 8; ++cf) {
      bf16x8 b = *(const bf16x8*)&wB[cf * 16 + ar][ks * 32 + kg * 8];
      acc[cf] = __builtin_amdgcn_mfma_f32_16x16x32_bf16(a, b, acc[cf], 0, 0, 0);
    }
  }

#pragma unroll
  for (int cf = 0; cf < 8; ++cf)
#pragma unroll
    for (int reg = 0; reg < 4; ++reg) {
      float v = fmaxf(acc[cf][reg] + bias1[cf], 0.f);
      xs[wave * 16 + 4 * kg + reg][cf * 16 + ar] = (unsigned short)f2bf(v);
    }
  __syncthreads();

#pragma unroll
  for (int i = 0; i < 8; ++i) {
    int idx = t + i * 256;
    int r = idx >> 4, c8 = (idx & 15) << 3;
    *(uint4*)&wB[r][c8] = *(const uint4*)(WgT + r * 128 + c8);
  }
  __syncthreads();

#pragma unroll
  for (int cf = 0; cf < 8; ++cf) acc[cf] = (f32x4){0.f, 0.f, 0.f, 0.f};
#pragma unroll
  for (int ks = 0; ks < 4; ++ks) {
    bf16x8 a = *(const bf16x8*)&xs[wave * 16 + ar][ks * 32 + kg * 8];
#pragma unroll
    for (int cf = 0; cf < 8; ++cf) {
      bf16x8 b = *(const bf16x8*)&wB[cf * 16 + ar][ks * 32 + kg * 8];
      acc[cf] = __builtin_amdgcn_mfma_f32_16x16x32_bf16(a, b, acc[cf], 0, 0, 0);
    }
  }

#pragma unroll
  for (int cf = 0; cf < 8; ++cf)
#pragma unroll
    for (int reg = 0; reg < 4; ++reg) {
      int gr = rowBase + wave * 16 + 4 * kg + reg;
      if (gr < N)
        h2[(size_t)gr * D + cf * 16 + ar] = (unsigned short)f2bf(acc[cf][reg] * dnv[reg]);
    }
}

// ---------------- CSR aggregation: 2 nodes/wave (32 lanes x uint2 each), 16-deep, bf16 out ----------------

__global__ __launch_bounds__(256) void k_agg(const unsigned short* __restrict__ h2,
                                             const int* __restrict__ deg,
                                             const unsigned short* __restrict__ csr16,
                                             const float* __restrict__ bg,
                                             unsigned short* __restrict__ h3, int N, int cap,
                                             int NP8) {
  const int half = threadIdx.x >> 5;          // 0..7
  const int hl = threadIdx.x & 31;
  const int n = blockIdx.x * 8 + half;
  if (n >= N) return;
  const uint2* h2v = (const uint2*)h2;        // 32 uint2 per row
  // independent loads first (overlap the gather chain)
  uint2 vself = h2v[(size_t)n * 32 + hl];
  int dg = deg[degIdx(n, NP8)];
  float4 bgv = ((const float4*)bg)[hl];
  float dn = rsqrtf((float)(dg + 1));
  float a0 = 0.f, a1 = 0.f, a2 = 0.f, a3 = 0.f;
  int cnt = min(dg, cap);
  size_t base = (size_t)n * cap;
  int i = 0;
  for (; i + 16 <= cnt; i += 16) {
    uint4 pa = *(const uint4*)(csr16 + base + i);
    uint4 pb = *(const uint4*)(csr16 + base + i + 8);
    int s[16] = {(int)(pa.x & 0xFFFFu), (int)(pa.x >> 16),
                 (int)(pa.y & 0xFFFFu), (int)(pa.y >> 16),
                 (int)(pa.z & 0xFFFFu), (int)(pa.z >> 16),
                 (int)(pa.w & 0xFFFFu), (int)(pa.w >> 16),
                 (int)(pb.x & 0xFFFFu), (int)(pb.x >> 16),
                 (int)(pb.y & 0xFFFFu), (int)(pb.y >> 16),
                 (int)(pb.z & 0xFFFFu), (int)(pb.z >> 16),
                 (int)(pb.w & 0xFFFFu), (int)(pb.w >> 16)};
    uint2 v[16];
#pragma unroll
    for (int u = 0; u < 16; ++u) v[u] = h2v[(size_t)s[u] * 32 + hl];
#pragma unroll
    for (int u = 0; u < 16; ++u) {
      a0 += bf_lo(v[u].x); a1 += bf_hi(v[u].x);
      a2 += bf_lo(v[u].y); a3 += bf_hi(v[u].y);
    }
  }
  for (; i + 8 <= cnt; i += 8) {
    uint4 pk = *(const uint4*)(csr16 + base + i);
    int s[8] = {(int)(pk.x & 0xFFFFu), (int)(pk.x >> 16),
                (int)(pk.y & 0xFFFFu), (int)(pk.y >> 16),
                (int)(pk.z & 0xFFFFu), (int)(pk.z >> 16),
                (int)(pk.w & 0xFFFFu), (int)(pk.w >> 16)};
    uint2 v[8];
#pragma unroll
    for (int u = 0; u < 8; ++u) v[u] = h2v[(size_t)s[u] * 32 + hl];
#pragma unroll
    for (int u = 0; u < 8; ++u) {
      a0 += bf_lo(v[u].x); a1 += bf_hi(v[u].x);
      a2 += bf_lo(v[u].y); a3 += bf_hi(v[u].y);
    }
  }
  for (; i < cnt; ++i) {
    int s = csr16[base + i];
    uint2 v = h2v[(size_t)s * 32 + hl];
    a0 += bf_lo(v.x); a1 += bf_hi(v.x);
    a2 += bf_lo(v.y); a3 += bf_hi(v.y);
  }
  a0 += bf_lo(vself.x); a1 += bf_hi(vself.x);   // self-loop
  a2 += bf_lo(vself.y); a3 += bf_hi(vself.y);
  float r0 = fmaxf(fmaf(a0, dn, bgv.x), 0.f);
  float r1 = fmaxf(fmaf(a1, dn, bgv.y), 0.f);
  float r2 = fmaxf(fmaf(a2, dn, bgv.z), 0.f);
  float r3 = fmaxf(fmaf(a3, dn, bgv.w), 0.f);
  uint2 o;
  o.x = pack2bf(r0, r1);
  o.y = pack2bf(r2, r3);
  ((uint2*)h3)[(size_t)n * 32 + hl] = o;
}

// ---------------- final MFMA GEMM: out = h3 @ W2 + b2 (h3 bf16 in ws) ----------------

__global__ __launch_bounds__(256) void k_out(const unsigned short* __restrict__ h3,
                                             const unsigned short* __restrict__ W2T,
                                             const float* __restrict__ b2,
                                             float* __restrict__ out, int N) {
  __shared__ unsigned short xs[64][136];
  __shared__ unsigned short wB[128][136];
  const int t = threadIdx.x;
  const int wave = t >> 6, lane = t & 63;
  const int rowBase = blockIdx.x * 64;
  const int ar = lane & 15, kg = lane >> 4;

#pragma unroll
  for (int i = 0; i < 4; ++i) {
    int idx = t + i * 256;
    int r = idx >> 4, c8 = (idx & 15) << 3;
    uint4 v = make_uint4(0u, 0u, 0u, 0u);
    int gr = rowBase + r;
    if (gr < N) v = *(const uint4*)(h3 + (size_t)gr * D + c8);
    *(uint4*)&xs[r][c8] = v;
  }
#pragma unroll
  for (int i = 0; i < 8; ++i) {
    int idx = t + i * 256;
    int r = idx >> 4, c8 = (idx & 15) << 3;
    *(uint4*)&wB[r][c8] = *(const uint4*)(W2T + r * 128 + c8);
  }
  __syncthreads();

  float bias2[8];
#pragma unroll
  for (int cf = 0; cf < 8; ++cf) bias2[cf] = b2[cf * 16 + ar];

  f32x4 acc[8];
#pragma unroll
  for (int cf = 0; cf < 8; ++cf) acc[cf] = (f32x4){0.f, 0.f, 0.f, 0.f};
#pragma unroll
  for (int ks = 0; ks < 4; ++ks) {
    bf16x8 a8 = *(const bf16x8*)&xs[wave * 16 + ar][ks * 32 + kg * 8];
#pragma unroll
    for (int cf = 0; cf < 8; ++cf) {
      bf16x8 b8 = *(const bf16x8*)&wB[cf * 16 + ar][ks * 32 + kg * 8];
      acc[cf] = __builtin_amdgcn_mfma_f32_16x16x32_bf16(a8, b8, acc[cf], 0, 0, 0);
    }
  }

#pragma unroll
  for (int cf = 0; cf < 8; ++cf)
#pragma unroll
    for (int reg = 0; reg < 4; ++reg) {
      int gr = rowBase + wave * 16 + 4 * kg + reg;
      if (gr < N)
        out[(size_t)gr * D + cf * 16 + ar] = acc[cf][reg] + bias2[cf];
    }
}

// ---------------- launch ----------------

extern "C" void kernel_launch(void* const* d_in, const int* in_sizes, int n_in,
                              void* d_out, int out_size, void* d_ws, size_t ws_size,
                              hipStream_t stream) {
  const float* x  = (const float*)d_in[0];
  const int*   ei = (const int*)d_in[1];   // int32 [2,E]
  const float* W1 = (const float*)d_in[2];
  const float* b1 = (const float*)d_in[3];
  const float* Wg = (const float*)d_in[4];
  const float* bg = (const float*)d_in[5];
  const float* W2 = (const float*)d_in[6];
  const float* b2 = (const float*)d_in[7];
  const int N = in_sizes[0] / D;
  const int E = in_sizes[1] / 2;
  float* out = (float*)d_out;

  const int pb  = (E + FILL_CHUNK - 1) / FILL_CHUNK;  // packed-edge chunks
  const int NP8 = (N + 7) / 8;                        // permuted-deg partition stride
  const int ZN  = 8 * NP8;                            // deg array size (permuted)

  // workspace layout: h2 | h3 | WT | deg | csr16 | pk
  unsigned short* h2 = (unsigned short*)d_ws;        // N*128 bf16
  unsigned short* h3 = h2 + (size_t)N * D;           // N*128 bf16
  unsigned short* WT = h3 + (size_t)N * D;           // 3*16384 bf16
  int*   deg  = (int*)(WT + 3 * 16384);              // 8*NP8 (permuted layout)
  unsigned short* csr16 = (unsigned short*)(deg + ZN);// N*cap u16

  size_t fixed = (size_t)N * D * 4 + 3 * 16384 * 2 + (size_t)ZN * 4
               + (size_t)pb * FILL_CHUNK * 4 + 16;
  int cap;
  if (ws_size >= fixed + (size_t)N * 64 * 2)      cap = 64;  // bucket = one 128B line/node
  else if (ws_size >= fixed + (size_t)N * 48 * 2) cap = 48;
  else return;  // diagnostic guard

  // pk after csr16, 16B-aligned for uint4 access
  size_t pk_off = ((size_t)((char*)(csr16 + (size_t)N * cap) - (char*)d_ws) + 15) & ~(size_t)15;
  unsigned int* pk = (unsigned int*)((char*)d_ws + pk_off);

  const int nzb = (ZN + 255) >> 8;

  k_prep<<<3 + nzb + pb, 256, 0, stream>>>(W1, Wg, W2, WT, deg, ZN, ei, E, pk);
  k_fill<<<pb * 8, 256, 0, stream>>>(pk, deg, csr16, cap, NP8);
  k_mlp <<<(N + 63) / 64, 256, 0, stream>>>(x, WT, b1, WT + 16384, deg, h2, N, NP8);
  k_agg <<<(N + 7) / 8, 256, 0, stream>>>(h2, deg, csr16, bg, h3, N, cap, NP8);
  k_out <<<(N + 63) / 64, 256, 0, stream>>>(h3, WT + 2 * 16384, b2, out, N);
}